// Round 4
// baseline (773.023 us; speedup 1.0000x reference)
//
#include <hip/hip_runtime.h>

#define S_LEN 2048
#define BATCH 16
#define DIM   512
#define KVB   32
#define NT    (S_LEN / KVB)

typedef __bf16 bf16x8 __attribute__((ext_vector_type(8)));
typedef float  f32x4  __attribute__((ext_vector_type(4)));
typedef float  f32x16 __attribute__((ext_vector_type(16)));
typedef unsigned int u32x4 __attribute__((ext_vector_type(4)));

static __device__ __forceinline__ unsigned short f2bf(float f) {
    __bf16 h = (__bf16)f;
    return __builtin_bit_cast(unsigned short, h);
}
static __device__ __forceinline__ bf16x8 ld_bf8(const unsigned short* p) {
    u32x4 v = *reinterpret_cast<const u32x4*>(p);
    return __builtin_bit_cast(bf16x8, v);
}
static __device__ __forceinline__ f32x4 mfma16(bf16x8 a, bf16x8 b, f32x4 c) {
    return __builtin_amdgcn_mfma_f32_16x16x32_bf16(a, b, c, 0, 0, 0);
}
static __device__ __forceinline__ f32x16 mfma32(bf16x8 a, bf16x8 b, f32x16 c) {
    return __builtin_amdgcn_mfma_f32_32x32x16_bf16(a, b, c, 0, 0, 0);
}
static __device__ __forceinline__ void gload16(const unsigned short* g, unsigned short* l) {
    __builtin_amdgcn_global_load_lds(
        (const __attribute__((address_space(1))) unsigned int*)g,
        (__attribute__((address_space(3))) unsigned int*)l, 16, 0, 0);
}
static __device__ __forceinline__ void waitv(int) = delete;
#define WAITV(N) do { asm volatile("s_waitcnt vmcnt(" #N ")" ::: "memory"); \
                      __builtin_amdgcn_sched_barrier(0); } while (0)
static __device__ __forceinline__ void waitlg0() {
    asm volatile("s_waitcnt lgkmcnt(0)" ::: "memory");
    __builtin_amdgcn_sched_barrier(0);
}

// ---------------- pack Wv fp32 -> bf16 [512][512] ----------------
__global__ void pack_wv(const float* __restrict__ wv, unsigned short* __restrict__ out) {
    int i = blockIdx.x * blockDim.x + threadIdx.x;
    float4 v = reinterpret_cast<const float4*>(wv)[i];
    uint2 r;
    r.x = (unsigned)f2bf(v.x) | ((unsigned)f2bf(v.y) << 16);
    r.y = (unsigned)f2bf(v.z) | ((unsigned)f2bf(v.w) << 16);
    reinterpret_cast<uint2*>(out)[i] = r;
}

// ---------------- pack V^T: seq [S][B][D] f32 -> vt [B][D][S] bf16 ----------------
__global__ void pack_vt(const float* __restrict__ seq, unsigned short* __restrict__ vt) {
    __shared__ float tile[32][33];
    int b  = blockIdx.z;
    int d0 = blockIdx.y * 32;
    int s0 = blockIdx.x * 32;
    int t  = threadIdx.x;
    {
        int sl = t >> 3, c4 = (t & 7) * 4;
        float4 v = *reinterpret_cast<const float4*>(
            seq + (size_t)(s0 + sl) * (BATCH * DIM) + (size_t)b * DIM + d0 + c4);
        tile[sl][c4 + 0] = v.x; tile[sl][c4 + 1] = v.y;
        tile[sl][c4 + 2] = v.z; tile[sl][c4 + 3] = v.w;
    }
    __syncthreads();
    {
        int dl = t >> 3, s4 = (t & 7) * 4;
        uint2 r;
        r.x = (unsigned)f2bf(tile[s4 + 0][dl]) | ((unsigned)f2bf(tile[s4 + 1][dl]) << 16);
        r.y = (unsigned)f2bf(tile[s4 + 2][dl]) | ((unsigned)f2bf(tile[s4 + 3][dl]) << 16);
        *reinterpret_cast<uint2*>(
            vt + (size_t)b * DIM * S_LEN + (size_t)(d0 + dl) * S_LEN + s0 + s4) = r;
    }
}

// ---------------- value = tanh(seq_in @ Wv^T + bv) -> bf16 [B*S][512] ----------------
__global__ void __launch_bounds__(256) gemm_value(
        const float* __restrict__ seq, const unsigned short* __restrict__ wvb,
        const float* __restrict__ bv, unsigned short* __restrict__ val) {
    __shared__ unsigned short Asm[64][72];
    __shared__ unsigned short Bsm[64][72];
    int t  = threadIdx.x;
    int rb = blockIdx.x * 64;
    int cb = blockIdx.y * 64;
    int w = t >> 6, l = t & 63;
    int mi = w >> 1, ni = w & 1;
    int l15 = l & 15, lh = l >> 4;
    f32x4 acc[2][2] = {};

    int srow = t >> 2;
    int qc   = (t & 3) * 16;
    int gr = rb + srow;
    int sb = gr >> 11, ss = gr & 2047;
    const float* aSrc = seq + ((size_t)ss * BATCH + sb) * DIM + qc;
    const unsigned short* bSrc = wvb + (size_t)(cb + srow) * DIM + qc;

    for (int k0 = 0; k0 < DIM; k0 += 64) {
        unsigned short ar[16];
        #pragma unroll
        for (int j = 0; j < 4; ++j) {
            float4 v = *reinterpret_cast<const float4*>(aSrc + k0 + j * 4);
            ar[j * 4 + 0] = f2bf(v.x); ar[j * 4 + 1] = f2bf(v.y);
            ar[j * 4 + 2] = f2bf(v.z); ar[j * 4 + 3] = f2bf(v.w);
        }
        *reinterpret_cast<u32x4*>(&Asm[srow][qc])     = *reinterpret_cast<u32x4*>(&ar[0]);
        *reinterpret_cast<u32x4*>(&Asm[srow][qc + 8]) = *reinterpret_cast<u32x4*>(&ar[8]);
        u32x4 b0 = *reinterpret_cast<const u32x4*>(bSrc + k0);
        u32x4 b1 = *reinterpret_cast<const u32x4*>(bSrc + k0 + 8);
        *reinterpret_cast<u32x4*>(&Bsm[srow][qc])     = b0;
        *reinterpret_cast<u32x4*>(&Bsm[srow][qc + 8]) = b1;
        __syncthreads();
        #pragma unroll
        for (int kf = 0; kf < 2; ++kf) {
            bf16x8 af[2], bfm[2];
            #pragma unroll
            for (int i = 0; i < 2; ++i)
                af[i] = ld_bf8(&Asm[mi * 32 + i * 16 + l15][kf * 32 + lh * 8]);
            #pragma unroll
            for (int j = 0; j < 2; ++j)
                bfm[j] = ld_bf8(&Bsm[ni * 32 + j * 16 + l15][kf * 32 + lh * 8]);
            #pragma unroll
            for (int i = 0; i < 2; ++i)
                #pragma unroll
                for (int j = 0; j < 2; ++j)
                    acc[i][j] = mfma16(af[i], bfm[j], acc[i][j]);
        }
        __syncthreads();
    }
    #pragma unroll
    for (int i = 0; i < 2; ++i) {
        #pragma unroll
        for (int j = 0; j < 2; ++j) {
            int gcol = cb + ni * 32 + j * 16 + l15;
            float bias = bv[gcol];
            #pragma unroll
            for (int r = 0; r < 4; ++r) {
                int grow = rb + mi * 32 + i * 16 + lh * 4 + r;
                float x = acc[i][j][r] + bias;
                val[(size_t)grow * DIM + gcol] = f2bf(tanhf(x));
            }
        }
    }
}

// ---------------- fused flash attention v4 ----------------
// QB=64, KVB=32, 8 waves, SINGLE-buffered K/V (LDS 80640 -> 2 blocks/CU).
// QK (mfma16): wave (qi=w&3, khi=w>>2). PV (mfma32): wave (qi2=w&1, dq=w>>1),
// O = 4 x f32x16 (32q x 128d). Split staging: stageK after QK barrier,
// stageV after PV barrier; counted vmcnt(4) waits (never drain mid-loop).
__global__ void __launch_bounds__(512, 4) attn_fused(
        const unsigned short* __restrict__ val, const unsigned short* __restrict__ vt,
        float* __restrict__ out) {
    extern __shared__ char smem[];
    unsigned short* Kt = (unsigned short*)smem;              // [32][512]  32KB
    unsigned short* Vt = (unsigned short*)(smem + 32768);    // [512][32]  32KB (g-swizzled)
    float*          Sb = (float*)(smem + 65536);             // [64][36]   9216B
    unsigned short* Pb = (unsigned short*)(smem + 74752);    // [64][40]   5120B
    float* stm = (float*)(smem + 79872);                     // [64]
    float* stl = stm + 64;
    float* sts = stm + 128;

    const int t = threadIdx.x;
    const int w = t >> 6, l = t & 63;
    const int l15 = l & 15, lh = l >> 4;
    const int l31 = l & 31, lh1 = l >> 5;

    int wg  = blockIdx.x;
    int swz = (wg & 7) * 64 + (wg >> 3);     // XCD-chunked, bijective (512 = 8*64)
    int b   = swz >> 5;
    int qb  = (swz & 31) * 64;

    const int qi = w & 3, khi = w >> 2;      // QK roles
    const int qi2 = w & 1, dq = w >> 1;      // PV roles

    const unsigned short* valb = val + (size_t)b * S_LEN * DIM;
    const unsigned short* vtb  = vt  + (size_t)b * DIM * S_LEN;

    if (t < 64) { stm[t] = -3.0e38f; stl[t] = 0.0f; }

    // Q fragments: rows qb + qi*16 + l15, full K=512 (64 VGPR)
    bf16x8 qf[16];
    {
        const unsigned short* qrow = valb + (size_t)(qb + qi * 16 + l15) * DIM + lh * 8;
        #pragma unroll
        for (int kf = 0; kf < 16; ++kf) qf[kf] = ld_bf8(qrow + kf * 32);
    }
    f32x16 o[4] = {};   // 32q x 128d

    auto stageK = [&](int tile) {
        int kv0 = tile * KVB;
        #pragma unroll
        for (int i = 0; i < 4; ++i) {
            int row = i * 8 + w;                  // row&7 == w (wave-uniform dst)
            gload16(valb + (size_t)(kv0 + row) * DIM + ((l ^ w) * 8),
                    Kt + row * 512);
        }
    };
    auto stageV = [&](int tile) {
        int kv0 = tile * KVB;
        #pragma unroll
        for (int i = 0; i < 4; ++i) {
            int d = i * 128 + w * 16 + (l >> 2);
            int g = (l & 3) ^ ((d >> 1) & 3);     // pre-swizzled source granule
            gload16(vtb + (size_t)d * S_LEN + kv0 + g * 8,
                    Vt + i * 4096 + w * 512);     // linear dest
        }
    };

    stageK(0);
    stageV(0);

    for (int kt = 0; kt < NT; ++kt) {
        WAITV(4);                                  // K(kt) landed (V(kt) may fly)
        __builtin_amdgcn_s_barrier();

        // ---- QK^T (mfma16), swizzled K tile ----
        {
            const unsigned short* kb = Kt + (khi * 16 + l15) * 512;
            int sw = (l15 & 7) << 3;
            f32x4 a0 = {}, a1 = {};
            __builtin_amdgcn_s_setprio(1);
            #pragma unroll
            for (int kf = 0; kf < 16; kf += 2) {
                bf16x8 k0 = ld_bf8(kb + ((kf * 32 + lh * 8) ^ sw));
                bf16x8 k1 = ld_bf8(kb + (((kf + 1) * 32 + lh * 8) ^ sw));
                a0 = mfma16(qf[kf], k0, a0);
                a1 = mfma16(qf[kf + 1], k1, a1);
            }
            __builtin_amdgcn_s_setprio(0);
            #pragma unroll
            for (int r = 0; r < 4; ++r)
                Sb[(qi * 16 + lh * 4 + r) * 36 + khi * 16 + l15] = a0[r] + a1[r];
        }
        waitlg0();
        __builtin_amdgcn_s_barrier();              // Sb visible; Kt free

        if (kt + 1 < NT) stageK(kt + 1);           // overlaps softmax + PV

        // ---- online softmax: 64 rows x 8 threads ----
        {
            int row = t >> 3, c0 = (t & 7) * 4;
            float4 sv = *reinterpret_cast<const float4*>(&Sb[row * 36 + c0]);
            float mt = fmaxf(fmaxf(sv.x, sv.y), fmaxf(sv.z, sv.w));
            #pragma unroll
            for (int m = 1; m <= 4; m <<= 1) mt = fmaxf(mt, __shfl_xor(mt, m, 64));
            float m_old = stm[row];
            float m_new = fmaxf(m_old, mt);
            float p0 = __expf(sv.x - m_new), p1 = __expf(sv.y - m_new);
            float p2 = __expf(sv.z - m_new), p3 = __expf(sv.w - m_new);
            float lt = (p0 + p1) + (p2 + p3);
            #pragma unroll
            for (int m = 1; m <= 4; m <<= 1) lt += __shfl_xor(lt, m, 64);
            uint2 pk;
            pk.x = (unsigned)f2bf(p0) | ((unsigned)f2bf(p1) << 16);
            pk.y = (unsigned)f2bf(p2) | ((unsigned)f2bf(p3) << 16);
            *reinterpret_cast<uint2*>(&Pb[row * 40 + c0]) = pk;
            if ((t & 7) == 0) {
                float alpha = __expf(m_old - m_new);
                sts[row] = alpha;
                stm[row] = m_new;
                stl[row] = stl[row] * alpha + lt;
            }
        }
        waitlg0();
        if (kt + 1 < NT) { WAITV(4); } else { WAITV(0); }   // V(kt) landed
        __builtin_amdgcn_s_barrier();              // P/stats ready

        // ---- rescale O + PV (mfma32) ----
        {
            f32x4 al[4];
            #pragma unroll
            for (int c = 0; c < 4; ++c)
                al[c] = *reinterpret_cast<const f32x4*>(sts + qi2 * 32 + 4 * lh1 + 8 * c);
            #pragma unroll
            for (int td = 0; td < 4; ++td)
                #pragma unroll
                for (int rr = 0; rr < 16; ++rr)
                    o[td][rr] *= al[rr >> 2][rr & 3];

            bf16x8 pa0 = ld_bf8(Pb + (qi2 * 32 + l31) * 40 + lh1 * 8);
            bf16x8 pa1 = ld_bf8(Pb + (qi2 * 32 + l31) * 40 + 16 + lh1 * 8);
            __builtin_amdgcn_s_setprio(1);
            #pragma unroll
            for (int td = 0; td < 4; ++td) {
                int d  = dq * 128 + td * 32 + l31;
                int dx = (d >> 1) & 3;
                bf16x8 v0 = ld_bf8(Vt + d * 32 + ((lh1 ^ dx) << 3));
                bf16x8 v1 = ld_bf8(Vt + d * 32 + (((2 + lh1) ^ dx) << 3));
                o[td] = mfma32(pa0, v0, o[td]);
                o[td] = mfma32(pa1, v1, o[td]);
            }
            __builtin_amdgcn_s_setprio(0);
        }
        waitlg0();
        __builtin_amdgcn_s_barrier();              // Vt free
        if (kt + 1 < NT) stageV(kt + 1);           // overlaps next QK
    }

    // ---- epilogue ----
    {
        f32x4 li[4];
        #pragma unroll
        for (int c = 0; c < 4; ++c) {
            f32x4 lv = *reinterpret_cast<const f32x4*>(stl + qi2 * 32 + 4 * lh1 + 8 * c);
            #pragma unroll
            for (int j = 0; j < 4; ++j) li[c][j] = 1.0f / lv[j];
        }
        #pragma unroll
        for (int td = 0; td < 4; ++td) {
            int col = dq * 128 + td * 32 + l31;
            #pragma unroll
            for (int rr = 0; rr < 16; ++rr) {
                int cr  = (rr & 3) + 8 * (rr >> 2) + 4 * lh1;
                int row = qb + qi2 * 32 + cr;
                out[(size_t)row * (BATCH * DIM) + (size_t)b * DIM + col] =
                    o[td][rr] * li[rr >> 2][rr & 3];
            }
        }
    }
}

extern "C" void kernel_launch(void* const* d_in, const int* in_sizes, int n_in,
                              void* d_out, int out_size, void* d_ws, size_t ws_size,
                              hipStream_t stream) {
    const float* seq = (const float*)d_in[0];   // [S][B][D] f32
    const float* wv  = (const float*)d_in[1];   // [D][D] f32
    const float* bv  = (const float*)d_in[2];   // [D] f32
    float* outp = (float*)d_out;                // [S][B][D] f32

    unsigned short* wsVal = (unsigned short*)d_ws;                          // 32 MB
    unsigned short* wsVt  = (unsigned short*)((char*)d_ws + 33554432);      // 32 MB
    unsigned short* wsWv  = (unsigned short*)((char*)d_ws + 67108864);      // 0.5 MB

    pack_wv<<<dim3(DIM * DIM / 4 / 256), dim3(256), 0, stream>>>(wv, wsWv);
    pack_vt<<<dim3(S_LEN / 32, DIM / 32, BATCH), dim3(256), 0, stream>>>(seq, wsVt);
    gemm_value<<<dim3(BATCH * S_LEN / 64, DIM / 64), dim3(256), 0, stream>>>(
        seq, wsWv, bv, wsVal);
    attn_fused<<<dim3(512), dim3(512), 80640, stream>>>(wsVal, wsVt, outp);
}

// Round 5
// 345.423 us; speedup vs baseline: 2.2379x; 2.2379x over previous
//
#include <hip/hip_runtime.h>

#define S_LEN 2048
#define BATCH 16
#define DIM   512
#define KVB   32
#define NT    (S_LEN / KVB)

typedef __bf16 bf16x8 __attribute__((ext_vector_type(8)));
typedef float  f32x4  __attribute__((ext_vector_type(4)));
typedef float  f32x16 __attribute__((ext_vector_type(16)));
typedef unsigned int u32x4 __attribute__((ext_vector_type(4)));

static __device__ __forceinline__ unsigned short f2bf(float f) {
    __bf16 h = (__bf16)f;
    return __builtin_bit_cast(unsigned short, h);
}
static __device__ __forceinline__ bf16x8 ld_bf8(const unsigned short* p) {
    u32x4 v = *reinterpret_cast<const u32x4*>(p);
    return __builtin_bit_cast(bf16x8, v);
}
static __device__ __forceinline__ f32x4 mfma16(bf16x8 a, bf16x8 b, f32x4 c) {
    return __builtin_amdgcn_mfma_f32_16x16x32_bf16(a, b, c, 0, 0, 0);
}
static __device__ __forceinline__ f32x16 mfma32(bf16x8 a, bf16x8 b, f32x16 c) {
    return __builtin_amdgcn_mfma_f32_32x32x16_bf16(a, b, c, 0, 0, 0);
}
static __device__ __forceinline__ void gload16(const unsigned short* g, unsigned short* l) {
    __builtin_amdgcn_global_load_lds(
        (const __attribute__((address_space(1))) unsigned int*)g,
        (__attribute__((address_space(3))) unsigned int*)l, 16, 0, 0);
}
#define WAITV(N) do { asm volatile("s_waitcnt vmcnt(" #N ")" ::: "memory"); \
                      __builtin_amdgcn_sched_barrier(0); } while (0)
static __device__ __forceinline__ void waitlg0() {
    asm volatile("s_waitcnt lgkmcnt(0)" ::: "memory");
    __builtin_amdgcn_sched_barrier(0);
}

// ---------------- pack Wv fp32 -> bf16 [512][512] ----------------
__global__ void pack_wv(const float* __restrict__ wv, unsigned short* __restrict__ out) {
    int i = blockIdx.x * blockDim.x + threadIdx.x;
    float4 v = reinterpret_cast<const float4*>(wv)[i];
    uint2 r;
    r.x = (unsigned)f2bf(v.x) | ((unsigned)f2bf(v.y) << 16);
    r.y = (unsigned)f2bf(v.z) | ((unsigned)f2bf(v.w) << 16);
    reinterpret_cast<uint2*>(out)[i] = r;
}

// ---------------- pack V^T: seq [S][B][D] f32 -> vt [B][D][S] bf16 ----------------
__global__ void pack_vt(const float* __restrict__ seq, unsigned short* __restrict__ vt) {
    __shared__ float tile[32][33];
    int b  = blockIdx.z;
    int d0 = blockIdx.y * 32;
    int s0 = blockIdx.x * 32;
    int t  = threadIdx.x;
    {
        int sl = t >> 3, c4 = (t & 7) * 4;
        float4 v = *reinterpret_cast<const float4*>(
            seq + (size_t)(s0 + sl) * (BATCH * DIM) + (size_t)b * DIM + d0 + c4);
        tile[sl][c4 + 0] = v.x; tile[sl][c4 + 1] = v.y;
        tile[sl][c4 + 2] = v.z; tile[sl][c4 + 3] = v.w;
    }
    __syncthreads();
    {
        int dl = t >> 3, s4 = (t & 7) * 4;
        uint2 r;
        r.x = (unsigned)f2bf(tile[s4 + 0][dl]) | ((unsigned)f2bf(tile[s4 + 1][dl]) << 16);
        r.y = (unsigned)f2bf(tile[s4 + 2][dl]) | ((unsigned)f2bf(tile[s4 + 3][dl]) << 16);
        *reinterpret_cast<uint2*>(
            vt + (size_t)b * DIM * S_LEN + (size_t)(d0 + dl) * S_LEN + s0 + s4) = r;
    }
}

// ---------------- value = tanh(seq_in @ Wv^T + bv) -> bf16 [B*S][512] ----------------
__global__ void __launch_bounds__(256) gemm_value(
        const float* __restrict__ seq, const unsigned short* __restrict__ wvb,
        const float* __restrict__ bv, unsigned short* __restrict__ val) {
    __shared__ unsigned short Asm[64][72];
    __shared__ unsigned short Bsm[64][72];
    int t  = threadIdx.x;
    int rb = blockIdx.x * 64;
    int cb = blockIdx.y * 64;
    int w = t >> 6, l = t & 63;
    int mi = w >> 1, ni = w & 1;
    int l15 = l & 15, lh = l >> 4;
    f32x4 acc[2][2] = {};

    int srow = t >> 2;
    int qc   = (t & 3) * 16;
    int gr = rb + srow;
    int sb = gr >> 11, ss = gr & 2047;
    const float* aSrc = seq + ((size_t)ss * BATCH + sb) * DIM + qc;
    const unsigned short* bSrc = wvb + (size_t)(cb + srow) * DIM + qc;

    for (int k0 = 0; k0 < DIM; k0 += 64) {
        unsigned short ar[16];
        #pragma unroll
        for (int j = 0; j < 4; ++j) {
            float4 v = *reinterpret_cast<const float4*>(aSrc + k0 + j * 4);
            ar[j * 4 + 0] = f2bf(v.x); ar[j * 4 + 1] = f2bf(v.y);
            ar[j * 4 + 2] = f2bf(v.z); ar[j * 4 + 3] = f2bf(v.w);
        }
        *reinterpret_cast<u32x4*>(&Asm[srow][qc])     = *reinterpret_cast<u32x4*>(&ar[0]);
        *reinterpret_cast<u32x4*>(&Asm[srow][qc + 8]) = *reinterpret_cast<u32x4*>(&ar[8]);
        u32x4 b0 = *reinterpret_cast<const u32x4*>(bSrc + k0);
        u32x4 b1 = *reinterpret_cast<const u32x4*>(bSrc + k0 + 8);
        *reinterpret_cast<u32x4*>(&Bsm[srow][qc])     = b0;
        *reinterpret_cast<u32x4*>(&Bsm[srow][qc + 8]) = b1;
        __syncthreads();
        #pragma unroll
        for (int kf = 0; kf < 2; ++kf) {
            bf16x8 af[2], bfm[2];
            #pragma unroll
            for (int i = 0; i < 2; ++i)
                af[i] = ld_bf8(&Asm[mi * 32 + i * 16 + l15][kf * 32 + lh * 8]);
            #pragma unroll
            for (int j = 0; j < 2; ++j)
                bfm[j] = ld_bf8(&Bsm[ni * 32 + j * 16 + l15][kf * 32 + lh * 8]);
            #pragma unroll
            for (int i = 0; i < 2; ++i)
                #pragma unroll
                for (int j = 0; j < 2; ++j)
                    acc[i][j] = mfma16(af[i], bfm[j], acc[i][j]);
        }
        __syncthreads();
    }
    #pragma unroll
    for (int i = 0; i < 2; ++i) {
        #pragma unroll
        for (int j = 0; j < 2; ++j) {
            int gcol = cb + ni * 32 + j * 16 + l15;
            float bias = bv[gcol];
            #pragma unroll
            for (int r = 0; r < 4; ++r) {
                int grow = rb + mi * 32 + i * 16 + lh * 4 + r;
                float x = acc[i][j][r] + bias;
                val[(size_t)grow * DIM + gcol] = f2bf(tanhf(x));
            }
        }
    }
}

// ---------------- fused flash attention v5 ----------------
// QB=64, KVB=32, 8 homogeneous waves. K,V,S all double-buffered (LDS 155392,
// 1 block/CU; occupancy is register-bound anyway). Software pipeline:
// iter kt: phase A = QK(kt+1) MFMA || softmax(kt) VALU (independent S bufs,
// overlap on separate pipes); phase B = rescale+PV(kt). Counted vmcnt:
// top WAITV(4) retires K(kt+1); WAITV(0) retires V(kt) (issued 1.5 iters ago).
__global__ void __launch_bounds__(512) attn_fused(
        const unsigned short* __restrict__ val, const unsigned short* __restrict__ vt,
        float* __restrict__ out) {
    extern __shared__ char smem[];
    unsigned short* Kt = (unsigned short*)smem;              // [2][32][512] 64KB
    unsigned short* Vt = (unsigned short*)(smem + 65536);    // [2][512][32] 64KB (g-swz)
    float*          Sb = (float*)(smem + 131072);            // [2][64][36] 18432B
    unsigned short* Pb = (unsigned short*)(smem + 149504);   // [64][40] 5120B
    float* stm = (float*)(smem + 154624);                    // [64]
    float* stl = stm + 64;
    float* sts = stm + 128;

    const int t = threadIdx.x;
    const int w = t >> 6, l = t & 63;
    const int l15 = l & 15, lh = l >> 4;
    const int l31 = l & 31, lh1 = l >> 5;

    int wg  = blockIdx.x;
    int swz = (wg & 7) * 64 + (wg >> 3);     // XCD-chunked, bijective (512 = 8*64)
    int b   = swz >> 5;
    int qb  = (swz & 31) * 64;

    const int qi = w & 3, khi = w >> 2;      // QK roles
    const int qi2 = w & 1, dq = w >> 1;      // PV roles

    const unsigned short* valb = val + (size_t)b * S_LEN * DIM;
    const unsigned short* vtb  = vt  + (size_t)b * DIM * S_LEN;

    if (t < 64) { stm[t] = -3.0e38f; stl[t] = 0.0f; }

    // Q fragments: rows qb + qi*16 + l15, full K=512 (64 VGPR)
    bf16x8 qf[16];
    {
        const unsigned short* qrow = valb + (size_t)(qb + qi * 16 + l15) * DIM + lh * 8;
        #pragma unroll
        for (int kf = 0; kf < 16; ++kf) qf[kf] = ld_bf8(qrow + kf * 32);
    }
    f32x16 o[4] = {};   // 32q x 128d

    auto stageK = [&](int tile) {
        int kv0 = tile * KVB;
        unsigned short* kb = Kt + (tile & 1) * 16384;
        #pragma unroll
        for (int i = 0; i < 4; ++i) {
            int row = i * 8 + w;                  // row&7 == w (wave-uniform dst)
            gload16(valb + (size_t)(kv0 + row) * DIM + ((l ^ w) * 8),
                    kb + row * 512);
        }
    };
    auto stageV = [&](int tile) {
        int kv0 = tile * KVB;
        unsigned short* vb = Vt + (tile & 1) * 16384;
        #pragma unroll
        for (int i = 0; i < 4; ++i) {
            int d = i * 128 + w * 16 + (l >> 2);
            int g = (l & 3) ^ ((d >> 1) & 3);     // pre-swizzled source granule
            gload16(vtb + (size_t)d * S_LEN + kv0 + g * 8,
                    vb + i * 4096 + w * 512);     // linear dest
        }
    };
    auto qk_compute = [&](int tile) {
        const unsigned short* kb = Kt + (tile & 1) * 16384 + (khi * 16 + l15) * 512;
        float* sdst = Sb + (tile & 1) * 2304;
        int sw = (l15 & 7) << 3;
        f32x4 a0 = {}, a1 = {};
        __builtin_amdgcn_s_setprio(1);
        #pragma unroll
        for (int kf = 0; kf < 16; kf += 2) {
            bf16x8 k0 = ld_bf8(kb + ((kf * 32 + lh * 8) ^ sw));
            bf16x8 k1 = ld_bf8(kb + (((kf + 1) * 32 + lh * 8) ^ sw));
            a0 = mfma16(qf[kf], k0, a0);
            a1 = mfma16(qf[kf + 1], k1, a1);
        }
        __builtin_amdgcn_s_setprio(0);
        #pragma unroll
        for (int r = 0; r < 4; ++r)
            sdst[(qi * 16 + lh * 4 + r) * 36 + khi * 16 + l15] = a0[r] + a1[r];
    };

    // ---- prologue ----
    stageK(0); stageK(1); stageV(0);
    WAITV(8);                                  // K(0) landed
    __builtin_amdgcn_s_barrier();
    qk_compute(0);                             // -> Sb[0]
    waitlg0();
    __builtin_amdgcn_s_barrier();

    for (int kt = 0; kt < NT; ++kt) {
        // ---- phase A: QK(kt+1) MFMA || softmax(kt) VALU ----
        if (kt + 1 < NT) qk_compute(kt + 1);
        {
            int row = t >> 3, c0 = (t & 7) * 4;
            const float* ssrc = Sb + (kt & 1) * 2304;
            float4 sv = *reinterpret_cast<const float4*>(&ssrc[row * 36 + c0]);
            float mt = fmaxf(fmaxf(sv.x, sv.y), fmaxf(sv.z, sv.w));
            #pragma unroll
            for (int m = 1; m <= 4; m <<= 1) mt = fmaxf(mt, __shfl_xor(mt, m, 64));
            float m_old = stm[row];
            float m_new = fmaxf(m_old, mt);
            float p0 = __expf(sv.x - m_new), p1 = __expf(sv.y - m_new);
            float p2 = __expf(sv.z - m_new), p3 = __expf(sv.w - m_new);
            float lt = (p0 + p1) + (p2 + p3);
            #pragma unroll
            for (int m = 1; m <= 4; m <<= 1) lt += __shfl_xor(lt, m, 64);
            uint2 pk;
            pk.x = (unsigned)f2bf(p0) | ((unsigned)f2bf(p1) << 16);
            pk.y = (unsigned)f2bf(p2) | ((unsigned)f2bf(p3) << 16);
            *reinterpret_cast<uint2*>(&Pb[row * 40 + c0]) = pk;
            if ((t & 7) == 0) {
                float alpha = __expf(m_old - m_new);
                sts[row] = alpha;
                stm[row] = m_new;
                stl[row] = stl[row] * alpha + lt;
            }
        }
        waitlg0();
        WAITV(0);                                  // V(kt) landed (issued long ago)
        if (kt + 2 < NT) stageK(kt + 2);
        if (kt + 1 < NT) stageV(kt + 1);
        __builtin_amdgcn_s_barrier();              // Pb/stats/V(kt) visible

        // ---- phase B: rescale O + PV(kt) ----
        {
            f32x4 al[4];
            #pragma unroll
            for (int c = 0; c < 4; ++c)
                al[c] = *reinterpret_cast<const f32x4*>(sts + qi2 * 32 + 4 * lh1 + 8 * c);
            #pragma unroll
            for (int td = 0; td < 4; ++td)
                #pragma unroll
                for (int rr = 0; rr < 16; ++rr)
                    o[td][rr] *= al[rr >> 2][rr & 3];

            bf16x8 pa0 = ld_bf8(Pb + (qi2 * 32 + l31) * 40 + lh1 * 8);
            bf16x8 pa1 = ld_bf8(Pb + (qi2 * 32 + l31) * 40 + 16 + lh1 * 8);
            const unsigned short* vb = Vt + (kt & 1) * 16384;
            __builtin_amdgcn_s_setprio(1);
            #pragma unroll
            for (int td = 0; td < 4; ++td) {
                int d  = dq * 128 + td * 32 + l31;
                int dx = (d >> 1) & 3;
                bf16x8 v0 = ld_bf8(vb + d * 32 + ((lh1 ^ dx) << 3));
                bf16x8 v1 = ld_bf8(vb + d * 32 + (((2 + lh1) ^ dx) << 3));
                o[td] = mfma32(pa0, v0, o[td]);
                o[td] = mfma32(pa1, v1, o[td]);
            }
            __builtin_amdgcn_s_setprio(0);
        }
        waitlg0();
        __builtin_amdgcn_s_barrier();              // WAR: Pb/Sb reusable next iter
    }

    // ---- epilogue ----
    {
        f32x4 li[4];
        #pragma unroll
        for (int c = 0; c < 4; ++c) {
            f32x4 lv = *reinterpret_cast<const f32x4*>(stl + qi2 * 32 + 4 * lh1 + 8 * c);
            #pragma unroll
            for (int j = 0; j < 4; ++j) li[c][j] = 1.0f / lv[j];
        }
        #pragma unroll
        for (int td = 0; td < 4; ++td) {
            int col = dq * 128 + td * 32 + l31;
            #pragma unroll
            for (int rr = 0; rr < 16; ++rr) {
                int cr  = (rr & 3) + 8 * (rr >> 2) + 4 * lh1;
                int row = qb + qi2 * 32 + cr;
                out[(size_t)row * (BATCH * DIM) + (size_t)b * DIM + col] =
                    o[td][rr] * li[rr >> 2][rr & 3];
            }
        }
    }
}

extern "C" void kernel_launch(void* const* d_in, const int* in_sizes, int n_in,
                              void* d_out, int out_size, void* d_ws, size_t ws_size,
                              hipStream_t stream) {
    const float* seq = (const float*)d_in[0];   // [S][B][D] f32
    const float* wv  = (const float*)d_in[1];   // [D][D] f32
    const float* bv  = (const float*)d_in[2];   // [D] f32
    float* outp = (float*)d_out;                // [S][B][D] f32

    unsigned short* wsVal = (unsigned short*)d_ws;                          // 32 MB
    unsigned short* wsVt  = (unsigned short*)((char*)d_ws + 33554432);      // 32 MB
    unsigned short* wsWv  = (unsigned short*)((char*)d_ws + 67108864);      // 0.5 MB

    pack_wv<<<dim3(DIM * DIM / 4 / 256), dim3(256), 0, stream>>>(wv, wsWv);
    pack_vt<<<dim3(S_LEN / 32, DIM / 32, BATCH), dim3(256), 0, stream>>>(seq, wsVt);
    gemm_value<<<dim3(BATCH * S_LEN / 64, DIM / 64), dim3(256), 0, stream>>>(
        seq, wsWv, bv, wsVal);
    attn_fused<<<dim3(512), dim3(512), 155392, stream>>>(wsVal, wsVt, outp);
}